// Round 10
// baseline (363.308 us; speedup 1.0000x reference)
//
#include <hip/hip_runtime.h>
#include <math.h>

// FairFightConvQAT: 4-layer fake-quantized CNN forward, fp32 in/out.
// Fused schedule (heavy passes 7 -> 4):
//   absmax(x) -> quantw -> conv1max -> K3{conv1store + L2max}
//   -> K4{L2store + L3max} -> K5{L3local + L4out}
// Layer-(k+1) absmax is computed INSIDE layer-k's store kernel from the
// locally requantized tile (scale s(h_k) is known there). Tiles at spacing 30
// with 32..36px local regions; neighboring blocks' overlapping global writes
// are byte-identical (same math) -> benign.
//
// Exactness: q_x in [0,127], q_w in [-128,127]; i8 MFMA accumulates exactly
// in i32 (|acc| <= 2.3e6 < 2^24). Requant y * (127/absmax), proven (r3..r9).
//
// ws: [0,32) slots (0..3 = x,h1,h2,h3 absmax; 4..7 = w1..w4 absmax)
//   256: qw1 f32 [pos][co] | 1024: qw4 f32 | 2048: wi8_2 | 5120: wi8_3
//   32768: h1 int8 NHWC 126x126x16 | +Q1: h2 int8 NHWC 124x124x16  (~128.06MB)

#define THREADS 256

typedef __attribute__((ext_vector_type(4))) int i32x4;

__device__ __forceinline__ int xcd_swz(int bid, int nwg) {
    return (bid & 7) * (nwg >> 3) + (bid >> 3);   // nwg % 8 == 0 everywhere
}
// LDS 16B-record swizzle: XOR addr bits[6:4] with rec bits[5:3]; bijective.
__device__ __forceinline__ int swzb(int rec) {
    return (rec << 4) ^ ((rec & 56) << 1);
}

__device__ __forceinline__ float block_reduce_max(float m, float* wred) {
#pragma unroll
    for (int off = 32; off > 0; off >>= 1)
        m = fmaxf(m, __shfl_down(m, off, 64));
    if ((threadIdx.x & 63) == 0) wred[threadIdx.x >> 6] = m;
    __syncthreads();
    return fmaxf(fmaxf(wred[0], wred[1]), fmaxf(wred[2], wred[3]));
}

__global__ void init_kernel(unsigned int* slots) {
    if (threadIdx.x < 8) slots[threadIdx.x] = 0u;
}

__global__ void fill_kernel(float* out, int n, float v) {
    int i = blockIdx.x * blockDim.x + threadIdx.x;
    int stride = gridDim.x * blockDim.x;
    for (; i < n; i += stride) out[i] = v;
}

__global__ __launch_bounds__(THREADS) void absmax4_kernel(
    const float4* __restrict__ x, int n4, unsigned int* __restrict__ slot) {
    __shared__ float wred[4];
    float m = 0.f;
    const int stride = gridDim.x * blockDim.x;
    for (int i = blockIdx.x * blockDim.x + threadIdx.x; i < n4; i += stride) {
        float4 v = x[i];
        m = fmaxf(fmaxf(fabsf(v.x), fabsf(v.y)),
                  fmaxf(fmaxf(fabsf(v.z), fabsf(v.w)), m));
    }
    m = block_reduce_max(m, wred);
    if (threadIdx.x == 0) atomicMax(slot, __float_as_uint(m));
}

// One block per weight tensor: absmax -> fake-quant.
// b0: qw1 f32 [pos][co]; b3: qw4 f32; b1/b2: wi8 i8-MFMA A-frags
// (i = g*1024 + lane*16 + ci; co=lane&15, q=lane>>4, pos=4g+q; pos>=9 -> 0).
__global__ __launch_bounds__(THREADS) void quant_w_kernel(
    const float* __restrict__ w1, const float* __restrict__ w2,
    const float* __restrict__ w3, const float* __restrict__ w4,
    float* __restrict__ qw1, float* __restrict__ qw4,
    signed char* __restrict__ wi8_2, signed char* __restrict__ wi8_3,
    unsigned int* __restrict__ slots) {
    __shared__ float wred[4];
    const float* w; int nel;
    switch (blockIdx.x) {
        case 0:  w = w1; nel = 144;  break;
        case 1:  w = w2; nel = 2304; break;
        case 2:  w = w3; nel = 2304; break;
        default: w = w4; nel = 64;   break;
    }
    float m = 0.f;
    for (int i = threadIdx.x; i < nel; i += blockDim.x)
        m = fmaxf(m, fabsf(w[i]));
    m = block_reduce_max(m, wred);
    if (threadIdx.x == 0) slots[4 + blockIdx.x] = __float_as_uint(m);
    const float s = fmaxf(m, 1e-8f) / 127.0f;

    if (blockIdx.x == 0) {
        for (int i = threadIdx.x; i < 144; i += blockDim.x) {
            int p = i % 9, o = i / 9;
            float q = fminf(fmaxf(rintf(w[i] / s), -128.f), 127.f);
            qw1[p * 16 + o] = q * s;
        }
    } else if (blockIdx.x == 3) {
        for (int i = threadIdx.x; i < 64; i += blockDim.x) {
            float q = fminf(fmaxf(rintf(w[i] / s), -128.f), 127.f);
            qw4[i] = q * s;
        }
    } else {
        signed char* wi8 = (blockIdx.x == 1) ? wi8_2 : wi8_3;
        for (int i = threadIdx.x; i < 3072; i += blockDim.x) {
            int ci = i & 15, lane = (i >> 4) & 63, g = i >> 10;
            int co = lane & 15, qq = lane >> 4;
            int pos = 4 * g + qq;
            float v = 0.f;
            if (pos < 9) {
                int ky = pos / 3, kx = pos % 3;
                v = fminf(fmaxf(rintf(w[((co * 16 + ci) * 3 + ky) * 3 + kx] / s),
                                -128.f), 127.f);
            }
            wi8[i] = (signed char)(int)v;
        }
    }
}

// --------- conv1max: y1 absmax only (VALU), 32-spacing, 4096 blocks --------
__global__ __launch_bounds__(THREADS) void conv1max_kernel(
    const float* __restrict__ x, const float* __restrict__ qw,
    const float* __restrict__ bias, unsigned int* __restrict__ slots) {
    constexpr int IH = 128, IW = 128, OH = 126, OW = 126;
    __shared__ float tile[34 * 34];
    __shared__ float wred[4];
    const int bid = xcd_swz(blockIdx.x, gridDim.x);
    const int n = bid >> 4, tr = bid & 15;
    const int oy0 = (tr >> 2) * 32, ox0 = (tr & 3) * 32;
    const float s_in = fmaxf(__uint_as_float(slots[0]), 1e-8f) / 127.0f;
    const float* xN = x + (size_t)n * IH * IW;

#pragma unroll
    for (int it = 0; it < 5; ++it) {
        int px = it * 256 + threadIdx.x;
        if (px < 1156) {
            int iy = px / 34, ix = px - iy * 34;
            int gy = min(oy0 + iy, IH - 1), gx = min(ox0 + ix, IW - 1);
            float q = rintf(xN[gy * IW + gx] / s_in);
            tile[px] = fminf(fmaxf(q, -128.f), 127.f);
        }
    }
    __syncthreads();

    const int tx = (threadIdx.x & 15) * 2, ty = (threadIdx.x >> 4) * 2;
    float p[4][4];
#pragma unroll
    for (int r = 0; r < 4; ++r) {
        const float* rp = &tile[(ty + r) * 34 + tx];
        p[r][0] = rp[0]; p[r][1] = rp[1]; p[r][2] = rp[2]; p[r][3] = rp[3];
    }
    float accm[16];
#pragma unroll
    for (int c = 0; c < 16; ++c) accm[c] = -3.0e38f;

#pragma unroll
    for (int sy = 0; sy < 2; ++sy)
#pragma unroll
    for (int sx = 0; sx < 2; ++sx) {
        float acc[16];
#pragma unroll
        for (int c = 0; c < 16; ++c) acc[c] = 0.f;
#pragma unroll
        for (int ky = 0; ky < 3; ++ky)
#pragma unroll
        for (int kx = 0; kx < 3; ++kx) {
            const float xv = p[sy + ky][sx + kx];
            const float* wp = qw + (ky * 3 + kx) * 16;
#pragma unroll
            for (int co = 0; co < 16; ++co)
                acc[co] = fmaf(xv, wp[co], acc[co]);
        }
        const int oy = oy0 + ty + sy, ox = ox0 + tx + sx;
        if (oy < OH && ox < OW) {
#pragma unroll
            for (int co = 0; co < 16; ++co)
                accm[co] = fmaxf(accm[co], acc[co]);
        }
    }
    float m = 0.f;
#pragma unroll
    for (int co = 0; co < 16; ++co)
        m = fmaxf(m, fmaxf(fmaf(accm[co], s_in, bias[co]), 0.f));
    m = block_reduce_max(m, wred);
    if (threadIdx.x == 0) atomicMax(&slots[1], __float_as_uint(m));
}

// --------- K3: conv1-store (h1 34x34 local) + L2-MFMA absmax --------------
// spacing 30, grid 6400. Stage x 36x36 -> h1 q8 34x34 (LDS + global, overlap-
// identical) -> L2 i8-MFMA on local h1 -> y2 32x32 max -> slot2.
__global__ __launch_bounds__(THREADS) void k3_kernel(
    const float* __restrict__ x, const float* __restrict__ qw1,
    const float* __restrict__ b1, signed char* __restrict__ h1out,
    const signed char* __restrict__ wi8_2, const float* __restrict__ b2,
    unsigned int* __restrict__ slots) {
    __shared__ float xt[36 * 36];
    __shared__ signed char h1t[34 * 34 * 16 + 128];
    __shared__ float wred[4];
    const int bid = xcd_swz(blockIdx.x, gridDim.x);
    const int n = bid / 25, tr = bid % 25;
    const int ty = (tr / 5) * 30, tx = (tr % 5) * 30;
    const int tid = threadIdx.x;

    const float s_x = fmaxf(__uint_as_float(slots[0]), 1e-8f) / 127.0f;
    const float r1  = 127.0f / fmaxf(__uint_as_float(slots[1]), 1e-8f);
    const float* xN = x + (size_t)n * 128 * 128;

    for (int i = tid; i < 1296; i += THREADS) {
        int iy = i / 36, ix = i - iy * 36;
        int gy = min(ty + iy, 127), gx = min(tx + ix, 127);
        float q = rintf(xN[gy * 128 + gx] / s_x);   // exact div, as reference
        xt[i] = fminf(fmaxf(q, -128.f), 127.f);
    }
    __syncthreads();

    // conv1 -> h1 q8 on 34x34; LDS records + overlap-identical global write
    for (int p = tid; p < 1156; p += THREADS) {
        int py = p / 34, px = p - py * 34;
        float acc[16];
#pragma unroll
        for (int c = 0; c < 16; ++c) acc[c] = 0.f;
#pragma unroll
        for (int ky = 0; ky < 3; ++ky)
#pragma unroll
        for (int kx = 0; kx < 3; ++kx) {
            const float xv = xt[(py + ky) * 36 + px + kx];
            const float* wp = qw1 + (ky * 3 + kx) * 16;
#pragma unroll
            for (int co = 0; co < 16; ++co)
                acc[co] = fmaf(xv, wp[co], acc[co]);
        }
        unsigned pk[4] = {0u, 0u, 0u, 0u};
#pragma unroll
        for (int co = 0; co < 16; ++co) {
            float y = fmaxf(fmaf(acc[co], s_x, b1[co]), 0.f);
            float q8 = fminf(rintf(y * r1), 127.f);      // y >= 0
            pk[co >> 2] |= ((unsigned)(int)q8) << ((co & 3) * 8);
        }
        int4 v; v.x = pk[0]; v.y = pk[1]; v.z = pk[2]; v.w = pk[3];
        *(int4*)(h1t + swzb(p)) = v;
        const int gy = ty + py, gx = tx + px;
        if (gy <= 125 && gx <= 125)
            *(int4*)(h1out + ((size_t)(n * 126 + gy) * 126 + gx) * 16) = v;
    }

    i32x4 afrag[3];
#pragma unroll
    for (int g = 0; g < 3; ++g)
        afrag[g] = ((const i32x4*)wi8_2)[g * 64 + (tid & 63)];
    __syncthreads();

    // L2 i8-MFMA absmax on local 32x32
    const int lane = tid & 63, wv = tid >> 6;
    const int q = lane >> 4, col = lane & 15;
    const int wr = wv >> 1, wc = wv & 1;
    int drec[3];
#pragma unroll
    for (int g = 0; g < 3; ++g) {
        int pos = 4 * g + q;
        int dy = (pos < 9) ? pos / 3 : 0;
        int dx = (pos < 9) ? pos % 3 : 0;
        drec[g] = dy * 34 + dx;
    }
    const int ix2 = 16 * wc + col;
    int mi[4];
#pragma unroll
    for (int j = 0; j < 4; ++j) mi[j] = INT_MIN;

#pragma unroll 4
    for (int r = 0; r < 16; ++r) {
        const int iy2 = 16 * wr + r;
        const int rec = iy2 * 34 + ix2;
        i32x4 acc = {0, 0, 0, 0};
#pragma unroll
        for (int g = 0; g < 3; ++g) {
            i32x4 b = *(const i32x4*)(h1t + swzb(rec + drec[g]));
            acc = __builtin_amdgcn_mfma_i32_16x16x64_i8(afrag[g], b, acc, 0, 0, 0);
        }
        if (ty + iy2 <= 123 && tx + ix2 <= 123) {
#pragma unroll
            for (int j = 0; j < 4; ++j)
                mi[j] = (acc[j] > mi[j]) ? acc[j] : mi[j];
        }
    }
    const float s1  = fmaxf(__uint_as_float(slots[1]), 1e-8f) / 127.0f;
    const float sw2 = fmaxf(__uint_as_float(slots[5]), 1e-8f) / 127.0f;
    const float sxw = s1 * sw2;
    float m = 0.f;
#pragma unroll
    for (int j = 0; j < 4; ++j)
        m = fmaxf(m, fmaxf(fmaf((float)mi[j], sxw, b2[q * 4 + j]), 0.f));
    m = block_reduce_max(m, wred);
    if (tid == 0) atomicMax(&slots[2], __float_as_uint(m));
}

// --------- K4: L2-store (h2 32x32) + L3-MFMA absmax (30x30 coverage) -------
__global__ __launch_bounds__(THREADS) void k4_kernel(
    const signed char* __restrict__ h1, const signed char* __restrict__ wi8_2,
    const float* __restrict__ b2, signed char* __restrict__ h2out,
    const signed char* __restrict__ wi8_3, const float* __restrict__ b3,
    unsigned int* __restrict__ slots) {
    __shared__ signed char h1t[34 * 34 * 16 + 128];
    __shared__ signed char h2t[32 * 32 * 16 + 128];
    __shared__ float wred[4];
    const int bid = xcd_swz(blockIdx.x, gridDim.x);
    const int n = bid / 25, tr = bid % 25;
    const int ty = (tr / 5) * 30, tx = (tr % 5) * 30;
    const int tid = threadIdx.x, lane = tid & 63, wv = tid >> 6;
    const int q = lane >> 4, col = lane & 15;
    const int wr = wv >> 1, wc = wv & 1;

    const signed char* h1N = h1 + (size_t)n * 126 * 126 * 16;
#pragma unroll
    for (int it = 0; it < 5; ++it) {
        int p = it * 256 + tid;
        if (p < 1156) {
            int iy = p / 34, ix = p - iy * 34;
            int gy = min(ty + iy, 125), gx = min(tx + ix, 125);
            *(int4*)(h1t + swzb(p)) =
                *(const int4*)(h1N + ((size_t)gy * 126 + gx) * 16);
        }
    }
    i32x4 af2[3], af3[3];
#pragma unroll
    for (int g = 0; g < 3; ++g) {
        af2[g] = ((const i32x4*)wi8_2)[g * 64 + lane];
        af3[g] = ((const i32x4*)wi8_3)[g * 64 + lane];
    }
    __syncthreads();

    int d34[3], d32[3];
#pragma unroll
    for (int g = 0; g < 3; ++g) {
        int pos = 4 * g + q;
        int dy = (pos < 9) ? pos / 3 : 0;
        int dx = (pos < 9) ? pos % 3 : 0;
        d34[g] = dy * 34 + dx;
        d32[g] = dy * 32 + dx;
    }
    const float s1  = fmaxf(__uint_as_float(slots[1]), 1e-8f) / 127.0f;
    const float sw2 = fmaxf(__uint_as_float(slots[5]), 1e-8f) / 127.0f;
    const float sxw2 = s1 * sw2;
    const float r2 = 127.0f / fmaxf(__uint_as_float(slots[2]), 1e-8f);
    float b2j[4];
#pragma unroll
    for (int j = 0; j < 4; ++j) b2j[j] = b2[q * 4 + j];

    const int ix2 = 16 * wc + col;
    signed char* h2N = h2out + (size_t)n * 124 * 124 * 16;

    // L2: compute + requant h2 32x32 -> LDS records + global (overlap-identical)
#pragma unroll 4
    for (int r = 0; r < 16; ++r) {
        const int iy2 = 16 * wr + r;
        const int rec = iy2 * 34 + ix2;
        i32x4 acc = {0, 0, 0, 0};
#pragma unroll
        for (int g = 0; g < 3; ++g) {
            i32x4 b = *(const i32x4*)(h1t + swzb(rec + d34[g]));
            acc = __builtin_amdgcn_mfma_i32_16x16x64_i8(af2[g], b, acc, 0, 0, 0);
        }
        unsigned pk = 0u;
#pragma unroll
        for (int j = 0; j < 4; ++j) {
            float y = fmaxf(fmaf((float)acc[j], sxw2, b2j[j]), 0.f);
            float q8 = fminf(rintf(y * r2), 127.f);
            pk |= ((unsigned)(int)q8) << (j * 8);
        }
        *(unsigned*)(h2t + swzb(iy2 * 32 + ix2) + q * 4) = pk;
        const int gy = ty + iy2, gx = tx + ix2;
        if (gy <= 123 && gx <= 123)
            *(unsigned*)(h2N + ((size_t)gy * 124 + gx) * 16 + q * 4) = pk;
    }
    __syncthreads();

    // L3 absmax on local h2 (valid sub-region 30x30; spacing 30 -> coverage)
    int mi[4];
#pragma unroll
    for (int j = 0; j < 4; ++j) mi[j] = INT_MIN;
#pragma unroll 4
    for (int r = 0; r < 16; ++r) {
        const int iy3 = 16 * wr + r;
        if (iy3 <= 29) {
            const int rec = iy3 * 32 + ix2;
            i32x4 acc = {0, 0, 0, 0};
#pragma unroll
            for (int g = 0; g < 3; ++g) {
                i32x4 b = *(const i32x4*)(h2t + swzb(rec + d32[g]));
                acc = __builtin_amdgcn_mfma_i32_16x16x64_i8(af3[g], b, acc, 0, 0, 0);
            }
            if (ix2 <= 29 && ty + iy3 <= 121 && tx + ix2 <= 121) {
#pragma unroll
                for (int j = 0; j < 4; ++j)
                    mi[j] = (acc[j] > mi[j]) ? acc[j] : mi[j];
            }
        }
    }
    const float s2  = fmaxf(__uint_as_float(slots[2]), 1e-8f) / 127.0f;
    const float sw3 = fmaxf(__uint_as_float(slots[6]), 1e-8f) / 127.0f;
    const float sxw3 = s2 * sw3;
    float m = 0.f;
#pragma unroll
    for (int j = 0; j < 4; ++j)
        m = fmaxf(m, fmaxf(fmaf((float)mi[j], sxw3, b3[q * 4 + j]), 0.f));
    m = block_reduce_max(m, wred);
    if (tid == 0) atomicMax(&slots[3], __float_as_uint(m));
}

// --------- K5: L3 local (h3 q8 32x32, no global) + L4 conv2x2+sigmoid ------
__global__ __launch_bounds__(THREADS) void k5_kernel(
    const signed char* __restrict__ h2, const signed char* __restrict__ wi8_3,
    const float* __restrict__ b3, const float* __restrict__ qw4,
    const float* __restrict__ b4, float* __restrict__ out,
    unsigned int* __restrict__ slots) {
    __shared__ signed char h2t[34 * 34 * 16 + 128];
    __shared__ signed char h3t[32 * 32 * 16 + 128];
    const int bid = xcd_swz(blockIdx.x, gridDim.x);
    const int n = bid / 25, tr = bid % 25;
    const int ty = (tr / 5) * 30, tx = (tr % 5) * 30;
    const int tid = threadIdx.x, lane = tid & 63, wv = tid >> 6;
    const int q = lane >> 4, col = lane & 15;
    const int wr = wv >> 1, wc = wv & 1;

    const signed char* h2N = h2 + (size_t)n * 124 * 124 * 16;
#pragma unroll
    for (int it = 0; it < 5; ++it) {
        int p = it * 256 + tid;
        if (p < 1156) {
            int iy = p / 34, ix = p - iy * 34;
            int gy = min(ty + iy, 123), gx = min(tx + ix, 123);
            *(int4*)(h2t + swzb(p)) =
                *(const int4*)(h2N + ((size_t)gy * 124 + gx) * 16);
        }
    }
    i32x4 af3[3];
#pragma unroll
    for (int g = 0; g < 3; ++g)
        af3[g] = ((const i32x4*)wi8_3)[g * 64 + lane];
    __syncthreads();

    int d34[3];
#pragma unroll
    for (int g = 0; g < 3; ++g) {
        int pos = 4 * g + q;
        int dy = (pos < 9) ? pos / 3 : 0;
        int dx = (pos < 9) ? pos % 3 : 0;
        d34[g] = dy * 34 + dx;
    }
    const float s2  = fmaxf(__uint_as_float(slots[2]), 1e-8f) / 127.0f;
    const float sw3 = fmaxf(__uint_as_float(slots[6]), 1e-8f) / 127.0f;
    const float sxw3 = s2 * sw3;
    const float r3 = 127.0f / fmaxf(__uint_as_float(slots[3]), 1e-8f);
    float b3j[4];
#pragma unroll
    for (int j = 0; j < 4; ++j) b3j[j] = b3[q * 4 + j];
    const int ix3 = 16 * wc + col;

    // L3: h3 q8 on local 32x32, LDS only (h3 never hits HBM)
#pragma unroll 4
    for (int r = 0; r < 16; ++r) {
        const int iy3 = 16 * wr + r;
        const int rec = iy3 * 34 + ix3;
        i32x4 acc = {0, 0, 0, 0};
#pragma unroll
        for (int g = 0; g < 3; ++g) {
            i32x4 b = *(const i32x4*)(h2t + swzb(rec + d34[g]));
            acc = __builtin_amdgcn_mfma_i32_16x16x64_i8(af3[g], b, acc, 0, 0, 0);
        }
        unsigned pk = 0u;
#pragma unroll
        for (int j = 0; j < 4; ++j) {
            float y = fmaxf(fmaf((float)acc[j], sxw3, b3j[j]), 0.f);
            float q8 = fminf(rintf(y * r3), 127.f);
            pk |= ((unsigned)(int)q8) << (j * 8);
        }
        *(unsigned*)(h3t + swzb(iy3 * 32 + ix3) + q * 4) = pk;
    }
    __syncthreads();

    // L4: conv2x2 16->1 + sigmoid on local h3, out 31x31 (spacing 30 coverage)
    const float s3 = fmaxf(__uint_as_float(slots[3]), 1e-8f) / 127.0f;
    const float bb = b4[0];
    float w[64];
#pragma unroll
    for (int i = 0; i < 64; ++i) w[i] = qw4[i];   // wave-uniform -> SGPR
    float* outN = out + (size_t)n * 121 * 121;

#pragma unroll
    for (int it = 0; it < 4; ++it) {
        int p = it * 256 + tid;
        if (p < 961) {
            int r = p / 31, c = p - r * 31;
            float acc = 0.f;
#pragma unroll
            for (int ky = 0; ky < 2; ++ky)
#pragma unroll
            for (int kx = 0; kx < 2; ++kx) {
                union { int4 v; signed char ch[16]; } u;
                u.v = *(const int4*)(h3t + swzb((r + ky) * 32 + (c + kx)));
#pragma unroll
                for (int ci = 0; ci < 16; ++ci)
                    acc = fmaf((float)u.ch[ci], w[(ci * 2 + ky) * 2 + kx], acc);
            }
            const int gy = ty + r, gx = tx + c;
            if (gy <= 120 && gx <= 120) {
                float y = fmaf(acc, s3, bb);
                outN[(size_t)gy * 121 + gx] = 1.0f / (1.0f + expf(-y));
            }
        }
    }
}

extern "C" void kernel_launch(void* const* d_in, const int* in_sizes, int n_in,
                              void* d_out, int out_size, void* d_ws, size_t ws_size,
                              hipStream_t stream) {
    (void)in_sizes; (void)n_in;
    const float* x  = (const float*)d_in[0];
    const float* w1 = (const float*)d_in[1];
    const float* b1 = (const float*)d_in[2];
    const float* w2 = (const float*)d_in[3];
    const float* b2 = (const float*)d_in[4];
    const float* w3 = (const float*)d_in[5];
    const float* b3 = (const float*)d_in[6];
    const float* w4 = (const float*)d_in[7];
    const float* b4 = (const float*)d_in[8];

    char* ws = (char*)d_ws;
    unsigned int* slots = (unsigned int*)ws;
    float* qw1 = (float*)(ws + 256);
    float* qw4 = (float*)(ws + 1024);
    signed char* wi8_2 = (signed char*)(ws + 2048);
    signed char* wi8_3 = (signed char*)(ws + 5120);

    const size_t Q1 = 65028096ULL;   // 256*126*126*16 int8 (h1)
    const size_t Q2 = 62980096ULL;   // 256*124*124*16 int8 (h2)
    signed char* qb1 = (signed char*)(ws + 32768);
    signed char* qb2 = (signed char*)(ws + 32768 + Q1);
    float* outp = (float*)d_out;

    const size_t need = 32768ULL + Q1 + Q2;  // ~128.06 MB
    if (ws_size < need) {
        float v = 100.0f + (float)(ws_size >> 20);
        hipLaunchKernelGGL(fill_kernel, dim3(1024), dim3(THREADS), 0, stream,
                           outp, out_size, v);
        return;
    }

    hipLaunchKernelGGL(init_kernel, dim3(1), dim3(64), 0, stream, slots);
    hipLaunchKernelGGL(absmax4_kernel, dim3(2048), dim3(THREADS), 0, stream,
                       (const float4*)x, 256 * 128 * 128 / 4, slots + 0);
    hipLaunchKernelGGL(quant_w_kernel, dim3(4), dim3(THREADS), 0, stream,
                       w1, w2, w3, w4, qw1, qw4, wi8_2, wi8_3, slots);

    hipLaunchKernelGGL(conv1max_kernel, dim3(256 * 16), dim3(THREADS), 0, stream,
                       x, qw1, b1, slots);
    const int fgrid = 256 * 25;   // spacing-30 tiles, 6400 blocks (%8==0)
    hipLaunchKernelGGL(k3_kernel, dim3(fgrid), dim3(THREADS), 0, stream,
                       x, qw1, b1, qb1, wi8_2, b2, slots);
    hipLaunchKernelGGL(k4_kernel, dim3(fgrid), dim3(THREADS), 0, stream,
                       qb1, wi8_2, b2, qb2, wi8_3, b3, slots);
    hipLaunchKernelGGL(k5_kernel, dim3(fgrid), dim3(THREADS), 0, stream,
                       qb2, wi8_3, b3, qw4, b4, outp, slots);
}

// Round 11
// 311.150 us; speedup vs baseline: 1.1676x; 1.1676x over previous
//
#include <hip/hip_runtime.h>
#include <math.h>

// FairFightConvQAT: 4-layer fake-quantized CNN forward, fp32 in/out.
// Schedule: absmax(x) -> quantw -> conv1max -> K3{conv1(i8 MFMA)+h1store+L2max}
//           -> K4{L2store+L3max} -> K5{L3local+L4out}
// K3 at spacing 32 (4096 blocks); K4/K5 at spacing 30 (6400 blocks, proven).
// conv1-in-K3 runs on the matrix pipe: k = dy*16+dx mapping, A = packed
// 3-byte weight rows (pad killed by zero A bytes), B = 4-byte x-row windows.
//
// Exactness: q in int8, i8 MFMA exact in i32 (|acc| <= 2.3e6 < 2^24).
// x-quant keeps exact division (mirrors reference); requant y*(127/absmax).
//
// ws: [0,32) slots (0..3 = x,h1,h2,h3 absmax; 4..7 = w1..w4 absmax)
//   256: qw1 f32 [pos][co] | 1024: qw1p (i8x4 packed, 64 dwords)
//   1536: qw4 f32 | 2048: wi8_2 | 5120: wi8_3
//   32768: h1 int8 NHWC 126x126x16 | +Q1: h2 int8 NHWC 124x124x16 (~128.06MB)

#define THREADS 256

typedef __attribute__((ext_vector_type(4))) int i32x4;

__device__ __forceinline__ int xcd_swz(int bid, int nwg) {
    return (bid & 7) * (nwg >> 3) + (bid >> 3);   // nwg % 8 == 0 everywhere
}
// LDS 16B-record swizzle: XOR addr bits[6:4] with rec bits[5:3]; bijective.
__device__ __forceinline__ int swzb(int rec) {
    return (rec << 4) ^ ((rec & 56) << 1);
}

__device__ __forceinline__ float block_reduce_max(float m, float* wred) {
#pragma unroll
    for (int off = 32; off > 0; off >>= 1)
        m = fmaxf(m, __shfl_down(m, off, 64));
    if ((threadIdx.x & 63) == 0) wred[threadIdx.x >> 6] = m;
    __syncthreads();
    return fmaxf(fmaxf(wred[0], wred[1]), fmaxf(wred[2], wred[3]));
}

__global__ void init_kernel(unsigned int* slots) {
    if (threadIdx.x < 8) slots[threadIdx.x] = 0u;
}

__global__ void fill_kernel(float* out, int n, float v) {
    int i = blockIdx.x * blockDim.x + threadIdx.x;
    int stride = gridDim.x * blockDim.x;
    for (; i < n; i += stride) out[i] = v;
}

__global__ __launch_bounds__(THREADS) void absmax4_kernel(
    const float4* __restrict__ x, int n4, unsigned int* __restrict__ slot) {
    __shared__ float wred[4];
    float m = 0.f;
    const int stride = gridDim.x * blockDim.x;
    for (int i = blockIdx.x * blockDim.x + threadIdx.x; i < n4; i += stride) {
        float4 v = x[i];
        m = fmaxf(fmaxf(fabsf(v.x), fabsf(v.y)),
                  fmaxf(fmaxf(fabsf(v.z), fabsf(v.w)), m));
    }
    m = block_reduce_max(m, wred);
    if (threadIdx.x == 0) atomicMax(slot, __float_as_uint(m));
}

// One block per weight tensor: absmax -> fake-quant.
// b0: qw1 f32 [pos][co] + qw1p packed (dword q*16+co = 3 weight bytes of tap
// row q for co, byte3=0; q==3 all zero); b3: qw4 f32; b1/b2: wi8 MFMA A-frags.
__global__ __launch_bounds__(THREADS) void quant_w_kernel(
    const float* __restrict__ w1, const float* __restrict__ w2,
    const float* __restrict__ w3, const float* __restrict__ w4,
    float* __restrict__ qw1, int* __restrict__ qw1p, float* __restrict__ qw4,
    signed char* __restrict__ wi8_2, signed char* __restrict__ wi8_3,
    unsigned int* __restrict__ slots) {
    __shared__ float wred[4];
    const float* w; int nel;
    switch (blockIdx.x) {
        case 0:  w = w1; nel = 144;  break;
        case 1:  w = w2; nel = 2304; break;
        case 2:  w = w3; nel = 2304; break;
        default: w = w4; nel = 64;   break;
    }
    float m = 0.f;
    for (int i = threadIdx.x; i < nel; i += blockDim.x)
        m = fmaxf(m, fabsf(w[i]));
    m = block_reduce_max(m, wred);
    if (threadIdx.x == 0) slots[4 + blockIdx.x] = __float_as_uint(m);
    const float s = fmaxf(m, 1e-8f) / 127.0f;

    if (blockIdx.x == 0) {
        for (int i = threadIdx.x; i < 144; i += blockDim.x) {
            int p = i % 9, o = i / 9;
            float q = fminf(fmaxf(rintf(w[i] / s), -128.f), 127.f);
            qw1[p * 16 + o] = q * s;
        }
        if (threadIdx.x < 64) {
            int qq = threadIdx.x >> 4, co = threadIdx.x & 15;
            unsigned pk = 0u;
            if (qq < 3) {
#pragma unroll
                for (int dx = 0; dx < 3; ++dx) {
                    float qv = fminf(fmaxf(rintf(w[co * 9 + qq * 3 + dx] / s),
                                           -128.f), 127.f);
                    pk |= ((unsigned)(int)qv & 0xffu) << (8 * dx);
                }
            }
            qw1p[threadIdx.x] = (int)pk;
        }
    } else if (blockIdx.x == 3) {
        for (int i = threadIdx.x; i < 64; i += blockDim.x) {
            float q = fminf(fmaxf(rintf(w[i] / s), -128.f), 127.f);
            qw4[i] = q * s;
        }
    } else {
        signed char* wi8 = (blockIdx.x == 1) ? wi8_2 : wi8_3;
        for (int i = threadIdx.x; i < 3072; i += blockDim.x) {
            int ci = i & 15, lane = (i >> 4) & 63, g = i >> 10;
            int co = lane & 15, qq = lane >> 4;
            int pos = 4 * g + qq;
            float v = 0.f;
            if (pos < 9) {
                int ky = pos / 3, kx = pos % 3;
                v = fminf(fmaxf(rintf(w[((co * 16 + ci) * 3 + ky) * 3 + kx] / s),
                                -128.f), 127.f);
            }
            wi8[i] = (signed char)(int)v;
        }
    }
}

// --------- conv1max: y1 absmax only (VALU), spacing 32, 4096 blocks --------
__global__ __launch_bounds__(THREADS) void conv1max_kernel(
    const float* __restrict__ x, const float* __restrict__ qw,
    const float* __restrict__ bias, unsigned int* __restrict__ slots) {
    constexpr int IH = 128, IW = 128, OH = 126, OW = 126;
    __shared__ float tile[34 * 34];
    __shared__ float wred[4];
    const int bid = xcd_swz(blockIdx.x, gridDim.x);
    const int n = bid >> 4, tr = bid & 15;
    const int oy0 = (tr >> 2) * 32, ox0 = (tr & 3) * 32;
    const float s_in = fmaxf(__uint_as_float(slots[0]), 1e-8f) / 127.0f;
    const float* xN = x + (size_t)n * IH * IW;

#pragma unroll
    for (int it = 0; it < 5; ++it) {
        int px = it * 256 + threadIdx.x;
        if (px < 1156) {
            int iy = px / 34, ix = px - iy * 34;
            int gy = min(oy0 + iy, IH - 1), gx = min(ox0 + ix, IW - 1);
            float q = rintf(xN[gy * IW + gx] / s_in);
            tile[px] = fminf(fmaxf(q, -128.f), 127.f);
        }
    }
    __syncthreads();

    const int tx = (threadIdx.x & 15) * 2, ty = (threadIdx.x >> 4) * 2;
    float p[4][4];
#pragma unroll
    for (int r = 0; r < 4; ++r) {
        const float* rp = &tile[(ty + r) * 34 + tx];
        p[r][0] = rp[0]; p[r][1] = rp[1]; p[r][2] = rp[2]; p[r][3] = rp[3];
    }
    float accm[16];
#pragma unroll
    for (int c = 0; c < 16; ++c) accm[c] = -3.0e38f;

#pragma unroll
    for (int sy = 0; sy < 2; ++sy)
#pragma unroll
    for (int sx = 0; sx < 2; ++sx) {
        float acc[16];
#pragma unroll
        for (int c = 0; c < 16; ++c) acc[c] = 0.f;
#pragma unroll
        for (int ky = 0; ky < 3; ++ky)
#pragma unroll
        for (int kx = 0; kx < 3; ++kx) {
            const float xv = p[sy + ky][sx + kx];
            const float* wp = qw + (ky * 3 + kx) * 16;
#pragma unroll
            for (int co = 0; co < 16; ++co)
                acc[co] = fmaf(xv, wp[co], acc[co]);
        }
        const int oy = oy0 + ty + sy, ox = ox0 + tx + sx;
        if (oy < OH && ox < OW) {
#pragma unroll
            for (int co = 0; co < 16; ++co)
                accm[co] = fmaxf(accm[co], acc[co]);
        }
    }
    float m = 0.f;
#pragma unroll
    for (int co = 0; co < 16; ++co)
        m = fmaxf(m, fmaxf(fmaf(accm[co], s_in, bias[co]), 0.f));
    m = block_reduce_max(m, wred);
    if (threadIdx.x == 0) atomicMax(&slots[1], __float_as_uint(m));
}

// --------- K3: conv1 via i8 MFMA -> h1 34x34 (LDS+global) + L2max ----------
// spacing 32, grid 4096. Stage quantized x int8 [36][40]; conv1 MFMA with
// k=dy*16+dx; requant h1; then L2 i8-MFMA absmax on local 32x32.
__global__ __launch_bounds__(THREADS) void k3_kernel(
    const float* __restrict__ x, const int* __restrict__ qw1p,
    const float* __restrict__ b1, signed char* __restrict__ h1out,
    const signed char* __restrict__ wi8_2, const float* __restrict__ b2,
    unsigned int* __restrict__ slots) {
    __shared__ signed char xq[40 * 40];            // 36x36 valid, stride 40
    __shared__ signed char h1t[34 * 34 * 16 + 128];
    __shared__ float wred[4];
    const int bid = xcd_swz(blockIdx.x, gridDim.x);
    const int n = bid >> 4, tr = bid & 15;
    const int ty = (tr >> 2) * 32, tx = (tr & 3) * 32;
    const int tid = threadIdx.x, lane = tid & 63, wv = tid >> 6;
    const int q = lane >> 4, col = lane & 15;

    const float s_x  = fmaxf(__uint_as_float(slots[0]), 1e-8f) / 127.0f;
    const float sw1  = fmaxf(__uint_as_float(slots[4]), 1e-8f) / 127.0f;
    const float sxw1 = s_x * sw1;
    const float r1   = 127.0f / fmaxf(__uint_as_float(slots[1]), 1e-8f);
    const float* xN = x + (size_t)n * 128 * 128;

    for (int i = tid; i < 1296; i += THREADS) {
        int iy = i / 36, ix = i - iy * 36;
        int gy = min(ty + iy, 127), gx = min(tx + ix, 127);
        float qf = rintf(xN[gy * 128 + gx] / s_x);   // exact div, as reference
        qf = fminf(fmaxf(qf, -128.f), 127.f);
        xq[iy * 40 + ix] = (signed char)(int)qf;
    }

    i32x4 a1 = {qw1p[q * 16 + col], 0, 0, 0};  // A lane(q=dy, col=co)
    i32x4 af2[3];
#pragma unroll
    for (int g = 0; g < 3; ++g)
        af2[g] = ((const i32x4*)wi8_2)[g * 64 + lane];
    float b1j[4], b2j[4];
#pragma unroll
    for (int j = 0; j < 4; ++j) { b1j[j] = b1[q * 4 + j]; b2j[j] = b2[q * 4 + j]; }
    __syncthreads();

    // conv1: h1 34x34 via MFMA. B lane(q=dy, col=px): 4-byte x-row window.
    for (int py = wv; py < 34; py += 4) {
#pragma unroll
        for (int g3 = 0; g3 < 3; ++g3) {
            const int pxx = g3 * 16 + col;
            const int base = (py + q) * 40 + (pxx & ~3);   // row <= 36 < 40
            unsigned lo = *(const unsigned*)(xq + base);
            unsigned hi = *(const unsigned*)(xq + base + 4);
            unsigned win = (unsigned)((((unsigned long long)hi << 32) | lo)
                                      >> ((pxx & 3) * 8));
            i32x4 b = {(int)win, 0, 0, 0};
            i32x4 z = {0, 0, 0, 0};
            i32x4 acc = __builtin_amdgcn_mfma_i32_16x16x64_i8(a1, b, z, 0, 0, 0);
            if (pxx < 34) {
                unsigned pk = 0u;
#pragma unroll
                for (int j = 0; j < 4; ++j) {
                    float y = fmaxf(fmaf((float)acc[j], sxw1, b1j[j]), 0.f);
                    float q8 = fminf(rintf(y * r1), 127.f);   // y >= 0
                    pk |= ((unsigned)(int)q8) << (j * 8);
                }
                *(unsigned*)(h1t + swzb(py * 34 + pxx) + q * 4) = pk;
                const int gy = ty + py, gx = tx + pxx;
                if (gy <= 125 && gx <= 125)
                    *(unsigned*)(h1out + ((size_t)(n * 126 + gy) * 126 + gx) * 16
                                 + q * 4) = pk;
            }
        }
    }
    __syncthreads();

    // L2 i8-MFMA absmax on local 32x32 (y2 dims 124: mask <=123)
    const int wr = wv >> 1, wc = wv & 1;
    int drec[3];
#pragma unroll
    for (int g = 0; g < 3; ++g) {
        int pos = 4 * g + q;
        int dy = (pos < 9) ? pos / 3 : 0;
        int dx = (pos < 9) ? pos % 3 : 0;
        drec[g] = dy * 34 + dx;
    }
    const int ix2 = 16 * wc + col;
    int mi[4];
#pragma unroll
    for (int j = 0; j < 4; ++j) mi[j] = INT_MIN;

#pragma unroll 4
    for (int r = 0; r < 16; ++r) {
        const int iy2 = 16 * wr + r;
        const int rec = iy2 * 34 + ix2;
        i32x4 acc = {0, 0, 0, 0};
#pragma unroll
        for (int g = 0; g < 3; ++g) {
            i32x4 b = *(const i32x4*)(h1t + swzb(rec + drec[g]));
            acc = __builtin_amdgcn_mfma_i32_16x16x64_i8(af2[g], b, acc, 0, 0, 0);
        }
        if (ty + iy2 <= 123 && tx + ix2 <= 123) {
#pragma unroll
            for (int j = 0; j < 4; ++j)
                mi[j] = (acc[j] > mi[j]) ? acc[j] : mi[j];
        }
    }
    const float s1  = fmaxf(__uint_as_float(slots[1]), 1e-8f) / 127.0f;
    const float sw2 = fmaxf(__uint_as_float(slots[5]), 1e-8f) / 127.0f;
    const float sxw = s1 * sw2;
    float m = 0.f;
#pragma unroll
    for (int j = 0; j < 4; ++j)
        m = fmaxf(m, fmaxf(fmaf((float)mi[j], sxw, b2j[j]), 0.f));
    m = block_reduce_max(m, wred);
    if (tid == 0) atomicMax(&slots[2], __float_as_uint(m));
}

// --------- K4: L2-store (h2 32x32) + L3-MFMA absmax (spacing 30) -----------
__global__ __launch_bounds__(THREADS) void k4_kernel(
    const signed char* __restrict__ h1, const signed char* __restrict__ wi8_2,
    const float* __restrict__ b2, signed char* __restrict__ h2out,
    const signed char* __restrict__ wi8_3, const float* __restrict__ b3,
    unsigned int* __restrict__ slots) {
    __shared__ signed char h1t[34 * 34 * 16 + 128];
    __shared__ signed char h2t[32 * 32 * 16 + 128];
    __shared__ float wred[4];
    const int bid = xcd_swz(blockIdx.x, gridDim.x);
    const int n = bid / 25, tr = bid % 25;
    const int ty = (tr / 5) * 30, tx = (tr % 5) * 30;
    const int tid = threadIdx.x, lane = tid & 63, wv = tid >> 6;
    const int q = lane >> 4, col = lane & 15;
    const int wr = wv >> 1, wc = wv & 1;

    const signed char* h1N = h1 + (size_t)n * 126 * 126 * 16;
#pragma unroll
    for (int it = 0; it < 5; ++it) {
        int p = it * 256 + tid;
        if (p < 1156) {
            int iy = p / 34, ix = p - iy * 34;
            int gy = min(ty + iy, 125), gx = min(tx + ix, 125);
            *(int4*)(h1t + swzb(p)) =
                *(const int4*)(h1N + ((size_t)gy * 126 + gx) * 16);
        }
    }
    i32x4 af2[3], af3[3];
#pragma unroll
    for (int g = 0; g < 3; ++g) {
        af2[g] = ((const i32x4*)wi8_2)[g * 64 + lane];
        af3[g] = ((const i32x4*)wi8_3)[g * 64 + lane];
    }
    __syncthreads();

    int d34[3], d32[3];
#pragma unroll
    for (int g = 0; g < 3; ++g) {
        int pos = 4 * g + q;
        int dy = (pos < 9) ? pos / 3 : 0;
        int dx = (pos < 9) ? pos % 3 : 0;
        d34[g] = dy * 34 + dx;
        d32[g] = dy * 32 + dx;
    }
    const float s1  = fmaxf(__uint_as_float(slots[1]), 1e-8f) / 127.0f;
    const float sw2 = fmaxf(__uint_as_float(slots[5]), 1e-8f) / 127.0f;
    const float sxw2 = s1 * sw2;
    const float r2 = 127.0f / fmaxf(__uint_as_float(slots[2]), 1e-8f);
    float b2j[4];
#pragma unroll
    for (int j = 0; j < 4; ++j) b2j[j] = b2[q * 4 + j];

    const int ix2 = 16 * wc + col;
    signed char* h2N = h2out + (size_t)n * 124 * 124 * 16;

#pragma unroll 4
    for (int r = 0; r < 16; ++r) {
        const int iy2 = 16 * wr + r;
        const int rec = iy2 * 34 + ix2;
        i32x4 acc = {0, 0, 0, 0};
#pragma unroll
        for (int g = 0; g < 3; ++g) {
            i32x4 b = *(const i32x4*)(h1t + swzb(rec + d34[g]));
            acc = __builtin_amdgcn_mfma_i32_16x16x64_i8(af2[g], b, acc, 0, 0, 0);
        }
        unsigned pk = 0u;
#pragma unroll
        for (int j = 0; j < 4; ++j) {
            float y = fmaxf(fmaf((float)acc[j], sxw2, b2j[j]), 0.f);
            float q8 = fminf(rintf(y * r2), 127.f);
            pk |= ((unsigned)(int)q8) << (j * 8);
        }
        *(unsigned*)(h2t + swzb(iy2 * 32 + ix2) + q * 4) = pk;
        const int gy = ty + iy2, gx = tx + ix2;
        if (gy <= 123 && gx <= 123)
            *(unsigned*)(h2N + ((size_t)gy * 124 + gx) * 16 + q * 4) = pk;
    }
    __syncthreads();

    int mi[4];
#pragma unroll
    for (int j = 0; j < 4; ++j) mi[j] = INT_MIN;
#pragma unroll 4
    for (int r = 0; r < 16; ++r) {
        const int iy3 = 16 * wr + r;
        if (iy3 <= 29) {
            const int rec = iy3 * 32 + ix2;
            i32x4 acc = {0, 0, 0, 0};
#pragma unroll
            for (int g = 0; g < 3; ++g) {
                i32x4 b = *(const i32x4*)(h2t + swzb(rec + d32[g]));
                acc = __builtin_amdgcn_mfma_i32_16x16x64_i8(af3[g], b, acc, 0, 0, 0);
            }
            if (ix2 <= 29 && ty + iy3 <= 121 && tx + ix2 <= 121) {
#pragma unroll
                for (int j = 0; j < 4; ++j)
                    mi[j] = (acc[j] > mi[j]) ? acc[j] : mi[j];
            }
        }
    }
    const float s2  = fmaxf(__uint_as_float(slots[2]), 1e-8f) / 127.0f;
    const float sw3 = fmaxf(__uint_as_float(slots[6]), 1e-8f) / 127.0f;
    const float sxw3 = s2 * sw3;
    float m = 0.f;
#pragma unroll
    for (int j = 0; j < 4; ++j)
        m = fmaxf(m, fmaxf(fmaf((float)mi[j], sxw3, b3[q * 4 + j]), 0.f));
    m = block_reduce_max(m, wred);
    if (tid == 0) atomicMax(&slots[3], __float_as_uint(m));
}

// --------- K5: L3 local (h3 q8 32x32, no global) + L4 conv2x2+sigmoid ------
__global__ __launch_bounds__(THREADS) void k5_kernel(
    const signed char* __restrict__ h2, const signed char* __restrict__ wi8_3,
    const float* __restrict__ b3, const float* __restrict__ qw4,
    const float* __restrict__ b4, float* __restrict__ out,
    unsigned int* __restrict__ slots) {
    __shared__ signed char h2t[34 * 34 * 16 + 128];
    __shared__ signed char h3t[32 * 32 * 16 + 128];
    const int bid = xcd_swz(blockIdx.x, gridDim.x);
    const int n = bid / 25, tr = bid % 25;
    const int ty = (tr / 5) * 30, tx = (tr % 5) * 30;
    const int tid = threadIdx.x, lane = tid & 63, wv = tid >> 6;
    const int q = lane >> 4, col = lane & 15;
    const int wr = wv >> 1, wc = wv & 1;

    const signed char* h2N = h2 + (size_t)n * 124 * 124 * 16;
#pragma unroll
    for (int it = 0; it < 5; ++it) {
        int p = it * 256 + tid;
        if (p < 1156) {
            int iy = p / 34, ix = p - iy * 34;
            int gy = min(ty + iy, 123), gx = min(tx + ix, 123);
            *(int4*)(h2t + swzb(p)) =
                *(const int4*)(h2N + ((size_t)gy * 124 + gx) * 16);
        }
    }
    i32x4 af3[3];
#pragma unroll
    for (int g = 0; g < 3; ++g)
        af3[g] = ((const i32x4*)wi8_3)[g * 64 + lane];
    __syncthreads();

    int d34[3];
#pragma unroll
    for (int g = 0; g < 3; ++g) {
        int pos = 4 * g + q;
        int dy = (pos < 9) ? pos / 3 : 0;
        int dx = (pos < 9) ? pos % 3 : 0;
        d34[g] = dy * 34 + dx;
    }
    const float s2  = fmaxf(__uint_as_float(slots[2]), 1e-8f) / 127.0f;
    const float sw3 = fmaxf(__uint_as_float(slots[6]), 1e-8f) / 127.0f;
    const float sxw3 = s2 * sw3;
    const float r3 = 127.0f / fmaxf(__uint_as_float(slots[3]), 1e-8f);
    float b3j[4];
#pragma unroll
    for (int j = 0; j < 4; ++j) b3j[j] = b3[q * 4 + j];
    const int ix3 = 16 * wc + col;

#pragma unroll 4
    for (int r = 0; r < 16; ++r) {
        const int iy3 = 16 * wr + r;
        const int rec = iy3 * 34 + ix3;
        i32x4 acc = {0, 0, 0, 0};
#pragma unroll
        for (int g = 0; g < 3; ++g) {
            i32x4 b = *(const i32x4*)(h2t + swzb(rec + d34[g]));
            acc = __builtin_amdgcn_mfma_i32_16x16x64_i8(af3[g], b, acc, 0, 0, 0);
        }
        unsigned pk = 0u;
#pragma unroll
        for (int j = 0; j < 4; ++j) {
            float y = fmaxf(fmaf((float)acc[j], sxw3, b3j[j]), 0.f);
            float q8 = fminf(rintf(y * r3), 127.f);
            pk |= ((unsigned)(int)q8) << (j * 8);
        }
        *(unsigned*)(h3t + swzb(iy3 * 32 + ix3) + q * 4) = pk;
    }
    __syncthreads();

    const float s3 = fmaxf(__uint_as_float(slots[3]), 1e-8f) / 127.0f;
    const float bb = b4[0];
    float w[64];
#pragma unroll
    for (int i = 0; i < 64; ++i) w[i] = qw4[i];   // wave-uniform -> SGPR
    float* outN = out + (size_t)n * 121 * 121;

#pragma unroll
    for (int it = 0; it < 4; ++it) {
        int p = it * 256 + tid;
        if (p < 961) {
            int r = p / 31, c = p - r * 31;
            float acc = 0.f;
#pragma unroll
            for (int ky = 0; ky < 2; ++ky)
#pragma unroll
            for (int kx = 0; kx < 2; ++kx) {
                union { int4 v; signed char ch[16]; } u;
                u.v = *(const int4*)(h3t + swzb((r + ky) * 32 + (c + kx)));
#pragma unroll
                for (int ci = 0; ci < 16; ++ci)
                    acc = fmaf((float)u.ch[ci], w[(ci * 2 + ky) * 2 + kx], acc);
            }
            const int gy = ty + r, gx = tx + c;
            if (gy <= 120 && gx <= 120) {
                float y = fmaf(acc, s3, bb);
                outN[(size_t)gy * 121 + gx] = 1.0f / (1.0f + expf(-y));
            }
        }
    }
}

extern "C" void kernel_launch(void* const* d_in, const int* in_sizes, int n_in,
                              void* d_out, int out_size, void* d_ws, size_t ws_size,
                              hipStream_t stream) {
    (void)in_sizes; (void)n_in;
    const float* x  = (const float*)d_in[0];
    const float* w1 = (const float*)d_in[1];
    const float* b1 = (const float*)d_in[2];
    const float* w2 = (const float*)d_in[3];
    const float* b2 = (const float*)d_in[4];
    const float* w3 = (const float*)d_in[5];
    const float* b3 = (const float*)d_in[6];
    const float* w4 = (const float*)d_in[7];
    const float* b4 = (const float*)d_in[8];

    char* ws = (char*)d_ws;
    unsigned int* slots = (unsigned int*)ws;
    float* qw1 = (float*)(ws + 256);
    int*   qw1p = (int*)(ws + 1024);
    float* qw4 = (float*)(ws + 1536);
    signed char* wi8_2 = (signed char*)(ws + 2048);
    signed char* wi8_3 = (signed char*)(ws + 5120);

    const size_t Q1 = 65028096ULL;   // 256*126*126*16 int8 (h1)
    const size_t Q2 = 62980096ULL;   // 256*124*124*16 int8 (h2)
    signed char* qb1 = (signed char*)(ws + 32768);
    signed char* qb2 = (signed char*)(ws + 32768 + Q1);
    float* outp = (float*)d_out;

    const size_t need = 32768ULL + Q1 + Q2;  // ~128.06 MB
    if (ws_size < need) {
        float v = 100.0f + (float)(ws_size >> 20);
        hipLaunchKernelGGL(fill_kernel, dim3(1024), dim3(THREADS), 0, stream,
                           outp, out_size, v);
        return;
    }

    hipLaunchKernelGGL(init_kernel, dim3(1), dim3(64), 0, stream, slots);
    hipLaunchKernelGGL(absmax4_kernel, dim3(2048), dim3(THREADS), 0, stream,
                       (const float4*)x, 256 * 128 * 128 / 4, slots + 0);
    hipLaunchKernelGGL(quant_w_kernel, dim3(4), dim3(THREADS), 0, stream,
                       w1, w2, w3, w4, qw1, qw1p, qw4, wi8_2, wi8_3, slots);

    hipLaunchKernelGGL(conv1max_kernel, dim3(256 * 16), dim3(THREADS), 0, stream,
                       x, qw1, b1, slots);
    hipLaunchKernelGGL(k3_kernel, dim3(256 * 16), dim3(THREADS), 0, stream,
                       x, qw1p, b1, qb1, wi8_2, b2, slots);
    const int fgrid = 256 * 25;   // spacing-30 tiles (%8==0)
    hipLaunchKernelGGL(k4_kernel, dim3(fgrid), dim3(THREADS), 0, stream,
                       qb1, wi8_2, b2, qb2, wi8_3, b3, slots);
    hipLaunchKernelGGL(k5_kernel, dim3(fgrid), dim3(THREADS), 0, stream,
                       qb2, wi8_3, b3, qw4, b4, outp, slots);
}